// Round 2
// baseline (43.643 us; speedup 1.0000x reference)
//
#include <hip/hip_runtime.h>
#include <stdint.h>

#define NV 4096
#define KS 17

typedef __attribute__((ext_vector_type(8))) short bf16x8;
typedef __attribute__((ext_vector_type(4))) float f32x4;

__device__ __forceinline__ unsigned short f2bf(float f) {
  union { float f; unsigned int u; } v; v.f = f;
  unsigned int r = v.u + 0x7FFF + ((v.u >> 16) & 1);  // RNE
  return (unsigned short)(r >> 16);
}

// fused prep: blocks 0..2047 convert feature_map f32->bf16 (4 elems/thread);
// blocks 2048..2319 permute weights (64 x 1088, f=c*17+k) -> Wb[k][o][c] bf16.
__global__ __launch_bounds__(256)
void prep(const float* __restrict__ fm, const float* __restrict__ w,
          unsigned short* __restrict__ fmb, unsigned short* __restrict__ wb) {
  int blk = blockIdx.x;
  if (blk < 2048) {
    int i = (blk * 256 + threadIdx.x) * 4;
    float4 v = *(const float4*)(fm + i);
    ushort4 o;
    o.x = f2bf(v.x); o.y = f2bf(v.y); o.z = f2bf(v.z); o.w = f2bf(v.w);
    *(ushort4*)(fmb + i) = o;
  } else {
    int t = (blk - 2048) * 256 + threadIdx.x;  // 0..69631 (= 17*64*64)
    int c = t & 63;
    int o = (t >> 6) & 63;
    int k = t >> 12;
    wb[t] = f2bf(w[o * 1088 + c * 17 + k]);
  }
}

// Barrier-free, LDS-free gather-GEMM.
// Block = 4 waves; wave owns 32 vertices x 32 out-channels.
// Block covers 64 vertices x 64 channels; 64 blocks/batch, 8 batches = 512 blocks.
// A-fragment (16B contiguous along channels) and B-fragment loaded straight
// from global (L2-resident) into VGPRs; 2-slot-deep register pipeline.
__global__ __launch_bounds__(256, 2)
void conv_main(const int* __restrict__ nbr, const unsigned short* __restrict__ fmb,
               const unsigned short* __restrict__ wb, const float* __restrict__ bias,
               float* __restrict__ out) {
  // bijective XCD swizzle: batch == XCD (64 blocks/batch, 8 XCDs)
  const int bid = blockIdx.x;
  const int wgid = (bid & 7) * 64 + (bid >> 3);

  const int tid = threadIdx.x;
  const int lane = tid & 63;
  const int lm = lane & 15;
  const int lk = lane >> 4;
  const int wv = tid >> 6;
  const int wm = wv >> 1;   // m-group 0..1 (32 rows each)
  const int wn = wv & 1;    // n-group 0..1 (32 cols each)

  const int b = wgid >> 6;
  const int vtile = (wgid & 63) * 64;
  const int rbase = vtile + wm * 32;
  const int obase = wn * 32;

  const int r0 = rbase + lm;
  const int r1 = rbase + 16 + lm;
  const int4* nr0 = (const int4*)(nbr + ((size_t)b * NV + r0) * 16);
  const int4* nr1 = (const int4*)(nbr + ((size_t)b * NV + r1) * 16);
  const bf16x8* fb = (const bf16x8*)(fmb + (size_t)b * NV * 64);
  const bf16x8* wq = (const bf16x8*)wb;

  // all 16 neighbor indices per owned row, up front (compile-time component sel)
  int4 iv0[4], iv1[4];
  #pragma unroll
  for (int j = 0; j < 4; ++j) { iv0[j] = nr0[j]; iv1[j] = nr1[j]; }

  const int obrow = (obase + lm) * 8 + lk;  // bf16x8 index of B row segment

  f32x4 acc[2][2];
  #pragma unroll
  for (int m = 0; m < 2; ++m)
    #pragma unroll
    for (int n = 0; n < 2; ++n)
      acc[m][n] = f32x4{0.f, 0.f, 0.f, 0.f};

  auto svsel = [&](int k, int which) -> int {
    if (k == 0) return which ? r1 : r0;
    const int j = (k - 1) >> 2, c = (k - 1) & 3;
    const int4 iv = which ? iv1[j] : iv0[j];
    return c == 0 ? iv.x : c == 1 ? iv.y : c == 2 ? iv.z : iv.w;
  };

  auto loadAB = [&](bf16x8 (&A)[2][2], bf16x8 (&B)[2][2], int k) {
    #pragma unroll
    for (int m = 0; m < 2; ++m) {
      const int sv = svsel(k, m);
      const bf16x8* p = fb + (size_t)sv * 8;
      A[m][0] = p[lk];        // channels lk*8 .. +7
      A[m][1] = p[4 + lk];    // channels 32+lk*8 .. +7
    }
    const bf16x8* q = wq + (size_t)k * 512 + obrow;
    #pragma unroll
    for (int n = 0; n < 2; ++n) {
      B[n][0] = q[n * 128];
      B[n][1] = q[n * 128 + 4];
    }
  };

  bf16x8 Ab[3][2][2], Bb[3][2][2];
  loadAB(Ab[0], Bb[0], 0);
  loadAB(Ab[1], Bb[1], 1);

  #pragma unroll
  for (int k = 0; k < KS; ++k) {
    if (k + 2 < KS) loadAB(Ab[(k + 2) % 3], Bb[(k + 2) % 3], k + 2);
    const int c = k % 3;
    #pragma unroll
    for (int h = 0; h < 2; ++h)
      #pragma unroll
      for (int m = 0; m < 2; ++m)
        #pragma unroll
        for (int n = 0; n < 2; ++n)
          acc[m][n] = __builtin_amdgcn_mfma_f32_16x16x32_bf16(
              Ab[c][m][h], Bb[c][n][h], acc[m][n], 0, 0, 0);
  }

  // C/D: col(out-channel) = lm, row(vertex) = lk*4 + r
  float bv0 = bias[obase + lm];
  float bv1 = bias[obase + 16 + lm];
  float* op = out + (size_t)b * NV * 64;
  #pragma unroll
  for (int m = 0; m < 2; ++m) {
    const int gv = vtile + wm * 32 + m * 16 + lk * 4;
    #pragma unroll
    for (int n = 0; n < 2; ++n) {
      const int o = obase + n * 16 + lm;
      const float bv = n ? bv1 : bv0;
      #pragma unroll
      for (int r = 0; r < 4; ++r) {
        float x = acc[m][n][r] + bv;
        op[(size_t)(gv + r) * 64 + o] = fmaxf(x, 0.f);
      }
    }
  }
}

extern "C" void kernel_launch(void* const* d_in, const int* in_sizes, int n_in,
                              void* d_out, int out_size, void* d_ws, size_t ws_size,
                              hipStream_t stream) {
  const int* nbr = (const int*)d_in[0];
  // d_in[1] = vertices (unused by the reference computation)
  const float* fm = (const float*)d_in[2];
  const float* w = (const float*)d_in[3];
  const float* bias = (const float*)d_in[4];
  float* out = (float*)d_out;

  unsigned short* fmb = (unsigned short*)d_ws;          // 8*4096*64 bf16 = 4 MB
  unsigned short* wb = fmb + (size_t)8 * NV * 64;       // 17*64*64 bf16

  prep<<<2320, 256, 0, stream>>>(fm, w, fmb, wb);
  conv_main<<<512, 256, 0, stream>>>(nbr, fmb, wb, bias, out);
}